// Round 14
// baseline (304.590 us; speedup 1.0000x reference)
//
#include <hip/hip_runtime.h>
#include <math.h>

#define NS   512
#define NF   15
#define NFP  16                 // padded LDS stride
#define NH   32
#define NTL  24
#define BPB  8                  // batches per block (2 per wave)
#define CHK  32                 // steps per staged chunk
#define NCHK (NS/CHK)           // 16
#define PERW (2*CHK*NF)         // 960 floats staged per wave per chunk
#define LOADS (PERW/64)         // 15 per-lane loads per chunk

__global__ __launch_bounds__(256, 1)
void gru_fused(const float* __restrict__ x,
               const float* __restrict__ Wd,  const float* __restrict__ bd,
               const float* __restrict__ Wih, const float* __restrict__ Whh,
               const float* __restrict__ bih, const float* __restrict__ bhh,
               const float* __restrict__ Wo,  const float* __restrict__ bo,
               float* __restrict__ out)
{
    const int tid  = threadIdx.x;
    const int l    = tid & 63;          // lane in wave
    const int w    = tid >> 6;          // wave in block
    const int half = (l >> 5) & 1;      // which batch of this wave
    const int i    = l & 31;            // hidden index
    const int grp  = tid >> 5;          // batch-in-block (0..7)
    const int gb   = blockIdx.x * BPB + grp;

    __shared__ float Wc[3*NH*NF];              // W_ih @ W_dense (96x15)
    __shared__ float xs[2][BPB][CHK*NFP];      // padded x staging
    __shared__ float hx[4][2][40];             // per-(wave,half) h vector

    // cooperative W_comb = W_ih @ W_dense
    for (int idx = tid; idx < 3*NH*NF; idx += 256) {
        const int g = idx / NF, f = idx - g*NF;
        float a = 0.f;
        #pragma unroll
        for (int k = 0; k < NH; ++k) a = fmaf(Wih[g*NH+k], Wd[k*NF+f], a);
        Wc[idx] = a;
    }
    // zero the f=15 pads in both staging buffers
    for (int e = tid; e < 2*BPB*CHK; e += 256) {
        const int buf = e >> 8, rr = e & 255, bb = rr >> 5, s = rr & 31;
        xs[buf][bb][s*NFP + NF] = 0.f;
    }

    // per-lane recurrent rows i, i+32, i+64 of W_hh
    float Wr[NH], Wz[NH], Wn[NH];
    #pragma unroll
    for (int j = 0; j < NH; ++j) {
        Wr[j] = Whh[(i       )*NH + j];
        Wz[j] = Whh[(i +   NH)*NH + j];
        Wn[j] = Whh[(i + 2*NH)*NH + j];
    }
    // folded biases
    float br = 0.f, bz = 0.f, bnx = 0.f;
    #pragma unroll
    for (int k = 0; k < NH; ++k) {
        br  = fmaf(Wih[(i       )*NH + k], bd[k], br);
        bz  = fmaf(Wih[(i +   NH)*NH + k], bd[k], bz);
        bnx = fmaf(Wih[(i + 2*NH)*NH + k], bd[k], bnx);
    }
    br  += bih[i]        + bhh[i];
    bz  += bih[i +   NH] + bhh[i +   NH];
    bnx += bih[i + 2*NH];
    const float bnh = bhh[i + 2*NH];
    const float wo  = Wo[i];
    const float bo0 = bo[0];

    __syncthreads();   // Wc + pads ready (only block barrier)

    float Cr[NFP], Cz[NFP], Cn[NFP];
    #pragma unroll
    for (int f = 0; f < NFP; ++f) {
        const bool ok = (f < NF);
        Cr[f] = ok ? Wc[(i       )*NF + f] : 0.f;
        Cz[f] = ok ? Wc[(i +   NH)*NF + f] : 0.f;
        Cn[f] = ok ? Wc[(i + 2*NH)*NF + f] : 0.f;
    }

    // wave-private staging geometry
    const float* xbase = x + (size_t)(blockIdx.x * BPB + w * 2) * NS * NF;
    int goff[LOADS], loff[LOADS], bsel[LOADS];
    #pragma unroll
    for (int k = 0; k < LOADS; ++k) {
        const int e   = k*64 + l;
        const int b   = (e >= 480) ? 1 : 0;
        const int rem = e - 480*b;
        const int s   = rem / NF, f = rem - s*NF;
        goff[k] = b * NS * NF + rem;
        loff[k] = s*NFP + f;
        bsel[k] = b;
    }

    float st[LOADS];
    #pragma unroll
    for (int k = 0; k < LOADS; ++k) st[k] = xbase[goff[k]];
    #pragma unroll
    for (int k = 0; k < LOADS; ++k) xs[0][w*2 + bsel[k]][loff[k]] = st[k];

    float xvA[NFP], xvB[NFP];
    {   // prologue: xvA = step 0 of chunk 0
        const float4* xp = (const float4*)(&xs[0][grp][0]);
        float4 x0 = xp[0], x1 = xp[1], x2 = xp[2], x3 = xp[3];
        xvA[0]=x0.x; xvA[1]=x0.y; xvA[2]=x0.z; xvA[3]=x0.w;
        xvA[4]=x1.x; xvA[5]=x1.y; xvA[6]=x1.z; xvA[7]=x1.w;
        xvA[8]=x2.x; xvA[9]=x2.y; xvA[10]=x2.z; xvA[11]=x2.w;
        xvA[12]=x3.x; xvA[13]=x3.y; xvA[14]=x3.z; xvA[15]=x3.w;
    }

    float h = 0.f;

    // One GRU step. XCUR: this step's x (in regs). XNXT: filled with next
    // step's x, read while hb loads are in flight. g-gate FMAs (h-independent)
    // are placed between the DS read issue and the hb consumption so they
    // execute in the DS latency shadow.
    #define GSTEP(SG, XCUR, XNXT, DOLOAD, NXTPTR)                              \
    {                                                                          \
        hx[w][half][i] = h;                                                    \
        __builtin_amdgcn_wave_barrier();                                       \
        const float4* hp_ = (const float4*)(&hx[w][half][0]);                  \
        const float4 H0=hp_[0], H1=hp_[1], H2=hp_[2], H3=hp_[3];               \
        const float4 H4=hp_[4], H5=hp_[5], H6=hp_[6], H7=hp_[7];               \
        if (DOLOAD) {                                                          \
            const float4* xp_ = (const float4*)(NXTPTR);                       \
            const float4 X0=xp_[0], X1=xp_[1], X2=xp_[2], X3=xp_[3];           \
            XNXT[0]=X0.x; XNXT[1]=X0.y; XNXT[2]=X0.z; XNXT[3]=X0.w;            \
            XNXT[4]=X1.x; XNXT[5]=X1.y; XNXT[6]=X1.z; XNXT[7]=X1.w;            \
            XNXT[8]=X2.x; XNXT[9]=X2.y; XNXT[10]=X2.z; XNXT[11]=X2.w;          \
            XNXT[12]=X3.x; XNXT[13]=X3.y; XNXT[14]=X3.z; XNXT[15]=X3.w;        \
        }                                                                      \
        /* input gates from XCUR (registers) — fills the DS wait */           \
        float gr = br, gz = bz, gnx = bnx;                                     \
        _Pragma("unroll")                                                      \
        for (int f = 0; f < NFP; ++f) {                                        \
            gr  = fmaf(Cr[f], XCUR[f], gr);                                    \
            gz  = fmaf(Cz[f], XCUR[f], gz);                                    \
            gnx = fmaf(Cn[f], XCUR[f], gnx);                                   \
        }                                                                      \
        const float hb[NH] = { H0.x,H0.y,H0.z,H0.w, H1.x,H1.y,H1.z,H1.w,       \
                               H2.x,H2.y,H2.z,H2.w, H3.x,H3.y,H3.z,H3.w,       \
                               H4.x,H4.y,H4.z,H4.w, H5.x,H5.y,H5.z,H5.w,       \
                               H6.x,H6.y,H6.z,H6.w, H7.x,H7.y,H7.z,H7.w };     \
        float dr0=0.f, dr1=0.f, dz0=0.f, dz1=0.f, dn0=0.f, dn1=0.f;            \
        _Pragma("unroll")                                                      \
        for (int j = 0; j < NH; j += 2) {                                      \
            dr0 = fmaf(Wr[j],   hb[j],   dr0);                                 \
            dr1 = fmaf(Wr[j+1], hb[j+1], dr1);                                 \
            dz0 = fmaf(Wz[j],   hb[j],   dz0);                                 \
            dz1 = fmaf(Wz[j+1], hb[j+1], dz1);                                 \
            dn0 = fmaf(Wn[j],   hb[j],   dn0);                                 \
            dn1 = fmaf(Wn[j+1], hb[j+1], dn1);                                 \
        }                                                                      \
        const float ar = gr + (dr0 + dr1);                                     \
        const float az = gz + (dz0 + dz1);                                     \
        const float dn = dn0 + dn1;                                            \
        const float r  = __builtin_amdgcn_rcpf(1.f + __expf(-ar));             \
        const float z  = __builtin_amdgcn_rcpf(1.f + __expf(-az));             \
        const float tt = gnx + r*(dn + bnh);                                   \
        const float e_ = __expf(-2.f*fabsf(tt));                               \
        float th = (1.f - e_) * __builtin_amdgcn_rcpf(1.f + e_);               \
        th = copysignf(th, tt);                                                \
        h = z*(h - th) + th;                                                   \
        if ((SG) >= NS - NTL) {                                                \
            float p = wo * h;                                                  \
            p += __int_as_float(__builtin_amdgcn_ds_swizzle(__float_as_int(p), 0x041F)); \
            p += __int_as_float(__builtin_amdgcn_ds_swizzle(__float_as_int(p), 0x081F)); \
            p += __int_as_float(__builtin_amdgcn_ds_swizzle(__float_as_int(p), 0x101F)); \
            p += __int_as_float(__builtin_amdgcn_ds_swizzle(__float_as_int(p), 0x201F)); \
            p += __int_as_float(__builtin_amdgcn_ds_swizzle(__float_as_int(p), 0x401F)); \
            if (i == 0) out[gb*NTL + (SG) - (NS - NTL)] = p + bo0;             \
        }                                                                      \
    }

    for (int c = 0; c < NCHK; ++c) {
        const float* curx = &xs[c & 1][grp][0];
        if (c + 1 < NCHK) {
            #pragma unroll
            for (int k = 0; k < LOADS; ++k)
                st[k] = xbase[goff[k] + (c+1)*CHK*NF];
        }
        #pragma unroll 1
        for (int s = 0; s < CHK; s += 2) {
            GSTEP(c*CHK + s,     xvA, xvB, true,           curx + (s+1)*NFP);
            GSTEP(c*CHK + s + 1, xvB, xvA, (s + 2 < CHK),  curx + (s+2)*NFP);
        }
        if (c + 1 < NCHK) {    // wave-private buffers: no block barrier needed
            #pragma unroll
            for (int k = 0; k < LOADS; ++k)
                xs[(c+1) & 1][w*2 + bsel[k]][loff[k]] = st[k];
            // reload xvA = step 0 of next chunk (in-wave DS ordering)
            const float4* xp = (const float4*)(&xs[(c+1) & 1][grp][0]);
            const float4 x0 = xp[0], x1 = xp[1], x2 = xp[2], x3 = xp[3];
            xvA[0]=x0.x; xvA[1]=x0.y; xvA[2]=x0.z; xvA[3]=x0.w;
            xvA[4]=x1.x; xvA[5]=x1.y; xvA[6]=x1.z; xvA[7]=x1.w;
            xvA[8]=x2.x; xvA[9]=x2.y; xvA[10]=x2.z; xvA[11]=x2.w;
            xvA[12]=x3.x; xvA[13]=x3.y; xvA[14]=x3.z; xvA[15]=x3.w;
        }
    }
    #undef GSTEP
}

extern "C" void kernel_launch(void* const* d_in, const int* in_sizes, int n_in,
                              void* d_out, int out_size, void* d_ws, size_t ws_size,
                              hipStream_t stream) {
    const float* x   = (const float*)d_in[0];
    const float* Wd  = (const float*)d_in[1];
    const float* bd  = (const float*)d_in[2];
    const float* Wih = (const float*)d_in[3];
    const float* Whh = (const float*)d_in[4];
    const float* bih = (const float*)d_in[5];
    const float* bhh = (const float*)d_in[6];
    const float* Wo  = (const float*)d_in[7];
    const float* bo  = (const float*)d_in[8];
    float* out = (float*)d_out;

    dim3 grid(2048 / BPB), block(256);
    hipLaunchKernelGGL(gru_fused, grid, block, 0, stream,
                       x, Wd, bd, Wih, Whh, bih, bhh, Wo, bo, out);
}

// Round 16
// 256.379 us; speedup vs baseline: 1.1880x; 1.1880x over previous
//
#include <hip/hip_runtime.h>
#include <math.h>

#define NS   512
#define NF   15
#define NFP  16                 // padded LDS stride
#define NH   32
#define NTL  24
#define BPB  8                  // batches per block (2 per wave)
#define CHK  32                 // steps per staged chunk
#define NCHK (NS/CHK)           // 16
#define PERW (2*CHK*NF)         // 960 floats staged per wave per chunk
#define LOADS (PERW/64)         // 15 per-lane loads per chunk

typedef float v2 __attribute__((ext_vector_type(2)));

__global__ __launch_bounds__(256, 1)
void gru_fused(const float* __restrict__ x,
               const float* __restrict__ Wd,  const float* __restrict__ bd,
               const float* __restrict__ Wih, const float* __restrict__ Whh,
               const float* __restrict__ bih, const float* __restrict__ bhh,
               const float* __restrict__ Wo,  const float* __restrict__ bo,
               float* __restrict__ out)
{
    const int tid  = threadIdx.x;
    const int l    = tid & 63;          // lane in wave
    const int w    = tid >> 6;          // wave in block
    const int half = (l >> 5) & 1;      // which batch of this wave
    const int i    = l & 31;            // hidden index
    const int grp  = tid >> 5;          // batch-in-block (0..7)
    const int gb   = blockIdx.x * BPB + grp;

    __shared__ float Wc[3*NH*NF];              // W_ih @ W_dense (96x15)
    __shared__ float xs[2][BPB][CHK*NFP];      // padded x staging
    __shared__ float hx[4][2][40];             // per-(wave,half) h vector

    // cooperative W_comb = W_ih @ W_dense
    for (int idx = tid; idx < 3*NH*NF; idx += 256) {
        const int g = idx / NF, f = idx - g*NF;
        float a = 0.f;
        #pragma unroll
        for (int k = 0; k < NH; ++k) a = fmaf(Wih[g*NH+k], Wd[k*NF+f], a);
        Wc[idx] = a;
    }
    // zero the f=15 pads in both staging buffers
    for (int e = tid; e < 2*BPB*CHK; e += 256) {
        const int buf = e >> 8, rr = e & 255, bb = rr >> 5, s = rr & 31;
        xs[buf][bb][s*NFP + NF] = 0.f;
    }

    // per-lane recurrent rows i, i+32, i+64 of W_hh, as float2 pairs
    v2 Wr2[NH/2], Wz2[NH/2], Wn2[NH/2];
    #pragma unroll
    for (int j = 0; j < NH/2; ++j) {
        Wr2[j] = (v2){ Whh[(i       )*NH + 2*j], Whh[(i       )*NH + 2*j+1] };
        Wz2[j] = (v2){ Whh[(i +   NH)*NH + 2*j], Whh[(i +   NH)*NH + 2*j+1] };
        Wn2[j] = (v2){ Whh[(i + 2*NH)*NH + 2*j], Whh[(i + 2*NH)*NH + 2*j+1] };
    }
    // folded biases
    float br = 0.f, bz = 0.f, bnx = 0.f;
    #pragma unroll
    for (int k = 0; k < NH; ++k) {
        br  = fmaf(Wih[(i       )*NH + k], bd[k], br);
        bz  = fmaf(Wih[(i +   NH)*NH + k], bd[k], bz);
        bnx = fmaf(Wih[(i + 2*NH)*NH + k], bd[k], bnx);
    }
    br  += bih[i]        + bhh[i];
    bz  += bih[i +   NH] + bhh[i +   NH];
    bnx += bih[i + 2*NH];
    const float bnh = bhh[i + 2*NH];
    const float wo  = Wo[i];
    const float bo0 = bo[0];

    __syncthreads();   // Wc + pads ready (only block barrier)

    v2 Cr2[NFP/2], Cz2[NFP/2], Cn2[NFP/2];
    #pragma unroll
    for (int p = 0; p < NFP/2; ++p) {
        const int f0 = 2*p, f1 = 2*p + 1;
        const float a0 = (f0 < NF) ? Wc[(i       )*NF + f0] : 0.f;
        const float a1 = (f1 < NF) ? Wc[(i       )*NF + f1] : 0.f;
        const float b0 = (f0 < NF) ? Wc[(i +   NH)*NF + f0] : 0.f;
        const float b1 = (f1 < NF) ? Wc[(i +   NH)*NF + f1] : 0.f;
        const float c0 = (f0 < NF) ? Wc[(i + 2*NH)*NF + f0] : 0.f;
        const float c1 = (f1 < NF) ? Wc[(i + 2*NH)*NF + f1] : 0.f;
        Cr2[p] = (v2){ a0, a1 };
        Cz2[p] = (v2){ b0, b1 };
        Cn2[p] = (v2){ c0, c1 };
    }

    // wave-private staging geometry
    const float* xbase = x + (size_t)(blockIdx.x * BPB + w * 2) * NS * NF;
    int goff[LOADS], loff[LOADS], bsel[LOADS];
    #pragma unroll
    for (int k = 0; k < LOADS; ++k) {
        const int e   = k*64 + l;
        const int b   = (e >= 480) ? 1 : 0;
        const int rem = e - 480*b;
        const int s   = rem / NF, f = rem - s*NF;
        goff[k] = b * NS * NF + rem;
        loff[k] = s*NFP + f;
        bsel[k] = b;
    }

    float st[LOADS];
    #pragma unroll
    for (int k = 0; k < LOADS; ++k) st[k] = xbase[goff[k]];
    #pragma unroll
    for (int k = 0; k < LOADS; ++k) xs[0][w*2 + bsel[k]][loff[k]] = st[k];

    float h = 0.f;
    for (int c = 0; c < NCHK; ++c) {
        const float* curx = &xs[c & 1][grp][0];
        if (c + 1 < NCHK) {
            #pragma unroll
            for (int k = 0; k < LOADS; ++k)
                st[k] = xbase[goff[k] + (c+1)*CHK*NF];
        }
        #pragma unroll 2
        for (int s = 0; s < CHK; ++s) {
            // publish h, read the full 32-vector back (broadcast b128 reads)
            hx[w][half][i] = h;
            __builtin_amdgcn_wave_barrier();
            const float4* hp = (const float4*)(&hx[w][half][0]);
            const float4 H0 = hp[0], H1 = hp[1], H2 = hp[2], H3 = hp[3];
            const float4 H4 = hp[4], H5 = hp[5], H6 = hp[6], H7 = hp[7];
            v2 hb2[NH/2] = { {H0.x,H0.y},{H0.z,H0.w}, {H1.x,H1.y},{H1.z,H1.w},
                             {H2.x,H2.y},{H2.z,H2.w}, {H3.x,H3.y},{H3.z,H3.w},
                             {H4.x,H4.y},{H4.z,H4.w}, {H5.x,H5.y},{H5.z,H5.w},
                             {H6.x,H6.y},{H6.z,H6.w}, {H7.x,H7.y},{H7.z,H7.w} };
            // x for this step: 4 vector reads (uniform addr within each half)
            const float4* xp = (const float4*)(curx + s*NFP);
            const float4 X0 = xp[0], X1 = xp[1], X2 = xp[2], X3 = xp[3];
            v2 xv2[NFP/2] = { {X0.x,X0.y},{X0.z,X0.w}, {X1.x,X1.y},{X1.z,X1.w},
                              {X2.x,X2.y},{X2.z,X2.w}, {X3.x,X3.y},{X3.z,X3.w} };

            // recurrent matvec: 48 packed FMAs, 2 accumulators per gate
            v2 dra = {0.f,0.f}, drb = {0.f,0.f};
            v2 dza = {0.f,0.f}, dzb = {0.f,0.f};
            v2 dna = {0.f,0.f}, dnb = {0.f,0.f};
            #pragma unroll
            for (int j = 0; j < NH/2; j += 2) {
                dra = __builtin_elementwise_fma(Wr2[j],   hb2[j],   dra);
                drb = __builtin_elementwise_fma(Wr2[j+1], hb2[j+1], drb);
                dza = __builtin_elementwise_fma(Wz2[j],   hb2[j],   dza);
                dzb = __builtin_elementwise_fma(Wz2[j+1], hb2[j+1], dzb);
                dna = __builtin_elementwise_fma(Wn2[j],   hb2[j],   dna);
                dnb = __builtin_elementwise_fma(Wn2[j+1], hb2[j+1], dnb);
            }
            // input path: 24 packed FMAs
            v2 gra = {0.f,0.f}, gza = {0.f,0.f}, gna = {0.f,0.f};
            #pragma unroll
            for (int p = 0; p < NFP/2; ++p) {
                gra = __builtin_elementwise_fma(Cr2[p], xv2[p], gra);
                gza = __builtin_elementwise_fma(Cz2[p], xv2[p], gza);
                gna = __builtin_elementwise_fma(Cn2[p], xv2[p], gna);
            }

            const v2 drv = dra + drb, dzv = dza + dzb, dnv = dna + dnb;
            const float ar = (br + gra.x + gra.y) + (drv.x + drv.y);
            const float az = (bz + gza.x + gza.y) + (dzv.x + dzv.y);
            const float dn = dnv.x + dnv.y;
            const float gnx = bnx + gna.x + gna.y;
            const float r  = __builtin_amdgcn_rcpf(1.f + __expf(-ar));
            const float z  = __builtin_amdgcn_rcpf(1.f + __expf(-az));
            const float tt = gnx + r*(dn + bnh);
            const float e  = __expf(-2.f*fabsf(tt));
            float th = (1.f - e) * __builtin_amdgcn_rcpf(1.f + e);
            th = copysignf(th, tt);
            h = z*(h - th) + th;          // (1-z)*tanh + z*h

            const int sg = c*CHK + s;
            if (sg >= NS - NTL) {
                float p = wo * h;          // reduce within each 32-lane half
                p += __int_as_float(__builtin_amdgcn_ds_swizzle(__float_as_int(p), 0x041F));
                p += __int_as_float(__builtin_amdgcn_ds_swizzle(__float_as_int(p), 0x081F));
                p += __int_as_float(__builtin_amdgcn_ds_swizzle(__float_as_int(p), 0x101F));
                p += __int_as_float(__builtin_amdgcn_ds_swizzle(__float_as_int(p), 0x201F));
                p += __int_as_float(__builtin_amdgcn_ds_swizzle(__float_as_int(p), 0x401F));
                if (i == 0) out[gb*NTL + sg - (NS - NTL)] = p + bo0;
            }
        }
        if (c + 1 < NCHK) {    // wave-private buffers: no block barrier needed
            #pragma unroll
            for (int k = 0; k < LOADS; ++k)
                xs[(c+1) & 1][w*2 + bsel[k]][loff[k]] = st[k];
        }
    }
}

extern "C" void kernel_launch(void* const* d_in, const int* in_sizes, int n_in,
                              void* d_out, int out_size, void* d_ws, size_t ws_size,
                              hipStream_t stream) {
    const float* x   = (const float*)d_in[0];
    const float* Wd  = (const float*)d_in[1];
    const float* bd  = (const float*)d_in[2];
    const float* Wih = (const float*)d_in[3];
    const float* Whh = (const float*)d_in[4];
    const float* bih = (const float*)d_in[5];
    const float* bhh = (const float*)d_in[6];
    const float* Wo  = (const float*)d_in[7];
    const float* bo  = (const float*)d_in[8];
    float* out = (float*)d_out;

    dim3 grid(2048 / BPB), block(256);
    hipLaunchKernelGGL(gru_fused, grid, block, 0, stream,
                       x, Wd, bd, Wih, Whh, bih, bhh, Wo, bo, out);
}